// Round 2
// 461.467 us; speedup vs baseline: 1.0000x; 1.0000x over previous
//
#include <hip/hip_runtime.h>

#define C 32
#define BINS (C * C)
#define NBLOCKS 2048
#define NTHREADS 256
#define GROUP_STRIDE ((NBLOCKS * NTHREADS) / 8)   // 65536 rows covered per grid stride
#define STRIDE2 (2 * GROUP_STRIDE)                // 131072 rows per unrolled iteration
#define FLT_EPS 1.1920928955078125e-07f

typedef float v4f __attribute__((ext_vector_type(4)));

// DPP cross-lane ops within the 8-lane group (no LDS/DS ops, pure VALU).
// ctrl 0xB1 = quad_perm(1,0,3,2) -> xor 1; 0x4E = quad_perm(2,3,0,1) -> xor 2;
// 0x141 = row_half_mirror -> lane i <-> i^7 (combines the two quads of the 8-group).
// All three stay within an aligned 8-lane group, whose validity is uniform.
// NOTE: dpp ctrl must be a literal at the builtin call -> template parameter.
template <int CTRL>
__device__ __forceinline__ float dpp_maxf(float x) {
    float o = __int_as_float(__builtin_amdgcn_update_dpp(
        0, __float_as_int(x), CTRL, 0xF, 0xF, true));
    return fmaxf(x, o);
}
template <int CTRL>
__device__ __forceinline__ unsigned int dpp_minu(unsigned int x) {
    unsigned int o = (unsigned int)__builtin_amdgcn_update_dpp(
        0, (int)x, CTRL, 0xF, 0xF, true);
    return x < o ? x : o;
}

// argmax over the 8-lane group's 32 floats (4 per lane), first-occurrence
// tie-break (min index among elements equal to the group max) — matches
// jnp.argmax. Result valid in ALL lanes of the group (full butterfly).
__device__ __forceinline__ int group_argmax(v4f v, int base) {
    float m = fmaxf(fmaxf(v.x, v.y), fmaxf(v.z, v.w));
    m = dpp_maxf<0xB1>(m);
    m = dpp_maxf<0x4E>(m);
    m = dpp_maxf<0x141>(m);
    unsigned int idx = 255u;                       // sentinel: lane has no max
    idx = (v.w == m) ? (unsigned int)(base + 3) : idx;
    idx = (v.z == m) ? (unsigned int)(base + 2) : idx;
    idx = (v.y == m) ? (unsigned int)(base + 1) : idx;
    idx = (v.x == m) ? (unsigned int)(base + 0) : idx;
    idx = dpp_minu<0xB1>(idx);
    idx = dpp_minu<0x4E>(idx);
    idx = dpp_minu<0x141>(idx);
    return (int)idx;
}

// 8 lanes per row, float4 each -> every load instr is a contiguous 1KB wave
// transaction. 2x-unrolled grid stride, software-pipelined one step ahead:
// 8 dwordx4 (128 B) outstanding per lane while the DPP reduce runs. The hot
// loop has ZERO DS ops (DPP reduce) so no lgkmcnt stalls between prefetches.
__global__ __launch_bounds__(NTHREADS) void hist_kernel(
    const float* __restrict__ yt,
    const float* __restrict__ yp,
    unsigned int* __restrict__ partial,  // [NBLOCKS][64]: 32 colsums, 32 diags
    int N)
{
    __shared__ unsigned int lhist[BINS];
    const int t = threadIdx.x;
    for (int i = t; i < BINS; i += NTHREADS) lhist[i] = 0u;
    __syncthreads();

    const int lane8 = t & 7;
    const int base = lane8 * 4;
    const float* pt = yt + base;
    const float* pp = yp + base;

    long long r0 = (long long)((blockIdx.x * NTHREADS + t) >> 3);
    long long r1 = r0 + GROUP_STRIDE;
    bool v0 = r0 < N;          // uniform within each 8-lane group -> DPP safe
    bool v1 = r1 < N;
    v4f a0, b0, a1, b1;
    if (v0) {
        a0 = __builtin_nontemporal_load((const v4f*)(pt + r0 * C));
        b0 = __builtin_nontemporal_load((const v4f*)(pp + r0 * C));
    }
    if (v1) {
        a1 = __builtin_nontemporal_load((const v4f*)(pt + r1 * C));
        b1 = __builtin_nontemporal_load((const v4f*)(pp + r1 * C));
    }

    while (v0) {
        const long long n0 = r0 + STRIDE2;
        const long long n1 = r1 + STRIDE2;
        const bool nv0 = n0 < N;
        const bool nv1 = n1 < N;
        v4f na0, nb0, na1, nb1;
        if (nv0) {  // prefetch next unrolled pair while we reduce this one
            na0 = __builtin_nontemporal_load((const v4f*)(pt + n0 * C));
            nb0 = __builtin_nontemporal_load((const v4f*)(pp + n0 * C));
        }
        if (nv1) {
            na1 = __builtin_nontemporal_load((const v4f*)(pt + n1 * C));
            nb1 = __builtin_nontemporal_load((const v4f*)(pp + n1 * C));
        }

        const int ti0 = group_argmax(a0, base);
        const int pi0 = group_argmax(b0, base);
        if (lane8 == 0) atomicAdd(&lhist[ti0 * C + pi0], 1u);
        if (v1) {
            const int ti1 = group_argmax(a1, base);
            const int pi1 = group_argmax(b1, base);
            // result is valid in all 8 lanes; lane 1 commits to spread issue
            if (lane8 == 1) atomicAdd(&lhist[ti1 * C + pi1], 1u);
        }

        r0 = n0; r1 = n1; v0 = nv0; v1 = nv1;
        a0 = na0; b0 = nb0; a1 = na1; b1 = nb1;
    }

    __syncthreads();
    if (t < 32) {
        unsigned int cs = 0;
        #pragma unroll
        for (int i = 0; i < C; ++i) cs += lhist[i * C + t];  // bank t for all i
        partial[(size_t)blockIdx.x * 64 + t] = cs;
    } else if (t < 64) {
        const int j = t - 32;
        partial[(size_t)blockIdx.x * 64 + t] = lhist[j * C + j];
    }
}

// Single block: sum [NBLOCKS][64] partials (coalesced), compute macro precision.
__global__ __launch_bounds__(1024) void finalize_kernel(
    const unsigned int* __restrict__ partial,
    const float* __restrict__ cm_in,
    float* __restrict__ out)
{
    __shared__ float sums[16][64];
    const int tid = threadIdx.x;
    const int col = tid & 63;
    const int kg = tid >> 6;   // 0..15

    unsigned int s = 0;
    #pragma unroll 8
    for (int k = kg * (NBLOCKS / 16); k < (kg + 1) * (NBLOCKS / 16); ++k)
        s += partial[(size_t)k * 64 + col];
    sums[kg][col] = (float)s;
    __syncthreads();

    if (tid < 64) {
        float tot = 0.0f;
        #pragma unroll
        for (int g = 0; g < 16; ++g) tot += sums[g][tid];
        sums[0][tid] = tot;
    }
    __syncthreads();

    if (tid < C) {
        const int j = tid;
        float pp = sums[0][j];       // histogram column sum for class j
        float tp = sums[0][C + j];   // histogram diagonal for class j
        float cmcol = 0.0f;
        #pragma unroll
        for (int i = 0; i < C; ++i) cmcol += cm_in[i * C + j];
        pp += cmcol;
        tp += cm_in[j * C + j];
        float prec = tp / (pp + FLT_EPS);
        #pragma unroll
        for (int m = 1; m < C; m <<= 1) prec += __shfl_xor(prec, m);
        if (j == 0) out[0] = prec * (1.0f / (float)C);
    }
}

extern "C" void kernel_launch(void* const* d_in, const int* in_sizes, int n_in,
                              void* d_out, int out_size, void* d_ws, size_t ws_size,
                              hipStream_t stream)
{
    const float* yt = (const float*)d_in[0];
    const float* yp = (const float*)d_in[1];
    const float* cm = (const float*)d_in[2];
    float* out = (float*)d_out;
    const int N = in_sizes[0] / C;

    unsigned int* partial = (unsigned int*)d_ws;  // NBLOCKS*64 u32 = 512 KB, fully overwritten

    hist_kernel<<<NBLOCKS, NTHREADS, 0, stream>>>(yt, yp, partial, N);
    finalize_kernel<<<1, 1024, 0, stream>>>(partial, cm, out);
}